// Round 1
// baseline (1917.308 us; speedup 1.0000x reference)
//
#include <hip/hip_runtime.h>
#include <math.h>

#define WW 512
#define HH 512
#define NPIX (WW*HH)
#define NSH 18  /* log2(NPIX) */
#define NXCD 8

typedef unsigned long long u64;
typedef unsigned int u32;

__device__ __forceinline__ u64 umax64(u64 a, u64 b) { return a > b ? a : b; }

// XCD-contiguous block remap. Grid (=total/256) is always nb*1024 -> divisible
// by 8, so this is a bijection. Each XCD gets a contiguous slab of pixel slots
// (at nb=8: exactly one image per XCD) so all neighbor-indexed reads
// (bnkey[v], labels[q], mcol4[lb], member pix4) hit the issuing XCD's own L2
// instead of being re-fetched by all 8 private L2s.
__device__ __forceinline__ int swz_idx() {
  int g = gridDim.x;                       // multiple of 8 by construction
  int b = (int)blockIdx.x;
  int nb2 = (b & (NXCD - 1)) * (g >> 3) + (b >> 3);
  return nb2 * 256 + (int)threadIdx.x;
}

// colors + gradient magnitude of pixel p (same __f*_rn sequence as always ->
// bit-identical to the reference's XLA lowering)
__device__ __forceinline__ float d_colg(const float* __restrict__ fb, int p, int pw, int ph,
                                        float col[3]) {
  float s = 0.f;
#pragma unroll
  for (int c = 0; c < 3; ++c) {
    const float* fc = fb + (size_t)c * NPIX;
    float v = fc[p];
    col[c] = v;
    float gx = (pw < WW - 1) ? __fsub_rn(fc[p + 1], v) : 0.f;
    float gy = (ph < HH - 1) ? __fsub_rn(fc[p + WW], v) : 0.f;
    float g = __fsqrt_rn(__fadd_rn(__fadd_rn(__fmul_rn(gx, gx), __fmul_rn(gy, gy)), 1e-12f));
    s = __fadd_rn(s, g);
  }
  return __fdiv_rn(s, 3.0f);
}

// packed key: (sim_bits<<32) | (NPIX-lb). max == {segment_max sim, then
// segment_min of tied neighbor labels}: sim>0 so bits are monotone; among
// sim-ties, max of NPIX-lb picks min lb. Bitwise symmetric in (a,b).
__device__ __forceinline__ u64 d_simkey(float a0, float a1, float a2, float ag,
                                        float b0, float b1, float b2, float bg, int lb) {
  float d0 = __fsub_rn(a0, b0);
  float d1 = __fsub_rn(a1, b1);
  float d2 = __fsub_rn(a2, b2);
  float ss = __fadd_rn(__fadd_rn(__fmul_rn(d0, d0), __fmul_rn(d1, d1)), __fmul_rn(d2, d2));
  float dc = __fsqrt_rn(__fadd_rn(ss, 1e-12f));
  float ge = __fmul_rn(0.5f, __fadd_rn(ag, bg));
  float t = __fadd_rn(__fdiv_rn(dc, 10.0f), __fdiv_rn(ge, 27.8f));
  float sim = (float)exp(-(double)t);   // ~correctly-rounded expf
  return ((u64)__float_as_uint(sim) << 32) | (u32)(NPIX - lb);
}

// fused prep + level-0 edge pass: per-pixel state (labels/cnt/pix4/mcol4) and
// the level-0 packed key over all 4 directed edges. Also zeroes the 8
// worklist counters (block 0; stream-ordered before any scan reads them).
__global__ __launch_bounds__(256) void k_prep0(const float* __restrict__ feat,
                                               int* __restrict__ labels,
                                               int* __restrict__ cnt,
                                               float4* __restrict__ pix4,
                                               float4* __restrict__ mcol4,
                                               u64* __restrict__ bnkey,
                                               int* __restrict__ ctr, int total) {
  if (blockIdx.x == 0 && threadIdx.x < 8) ctr[threadIdx.x] = 0;
  int idx = swz_idx();
  if (idx >= total) return;
  int b = idx >> NSH;
  int n = idx & (NPIX - 1);
  int w = n & (WW - 1);
  int h = n >> 9;
  const float* fb = feat + (size_t)b * 3 * NPIX;
  float ca[3];
  float ga = d_colg(fb, n, w, h, ca);
  labels[idx] = n;
  cnt[idx] = 1;
  float4 p4 = make_float4(ca[0], ca[1], ca[2], ga);
  pix4[idx] = p4;
  mcol4[idx] = p4;   // level-0 region mean == pixel (exact: x/1.0)
  u64 key = 0;
#pragma unroll
  for (int d = 0; d < 4; ++d) {
    bool ok; int q, qw, qh;
    switch (d) {
      case 0: ok = (w < WW - 1); q = n + 1;  qw = w + 1; qh = h;     break;
      case 1: ok = (w > 0);      q = n - 1;  qw = w - 1; qh = h;     break;
      case 2: ok = (h < HH - 1); q = n + WW; qw = w;     qh = h + 1; break;
      default: ok = (h > 0);     q = n - WW; qw = w;     qh = h - 1; break;
    }
    if (!ok) continue;
    float cb[3];
    float gb = d_colg(fb, q, qw, qh, cb);
    key = umax64(key, d_simkey(ca[0], ca[1], ca[2], ga, cb[0], cb[1], cb[2], gb, q));
  }
  bnkey[idx] = key;
}

// levels >=1: per-pixel edge pass. Each pixel max-reduces the packed keys of
// its own <=4 directed edges in registers and writes ONE coalesced u64.
__global__ __launch_bounds__(256) void k_pixedge(const int* __restrict__ labels,
                                                 const float4* __restrict__ mcol4,
                                                 u64* __restrict__ bnkey, int total) {
  int idx = swz_idx();
  if (idx >= total) return;
  int n = idx & (NPIX - 1);
  int base = idx - n;
  int w = n & (WW - 1);
  int h = n >> 9;
  int la = labels[idx];
  float4 ma = mcol4[base + la];
  u64 key = 0;
  int seen0 = -1, seen1 = -1, seen2 = -1;
#pragma unroll
  for (int d = 0; d < 4; ++d) {
    bool ok; int q;
    switch (d) {
      case 0: ok = (w < WW - 1); q = n + 1;  break;
      case 1: ok = (w > 0);      q = n - 1;  break;
      case 2: ok = (h < HH - 1); q = n + WW; break;
      default: ok = (h > 0);     q = n - WW; break;
    }
    if (!ok) continue;
    int lb = labels[base + q];
    if (lb == la || lb == seen0 || lb == seen1 || lb == seen2) continue;
    seen2 = seen1; seen1 = seen0; seen0 = lb;
    float4 mb = mcol4[base + lb];
    key = umax64(key, d_simkey(ma.x, ma.y, ma.z, ma.w, mb.x, mb.y, mb.z, mb.w, lb));
  }
  bnkey[idx] = key;
}

// in-place region reduction: each live rep with >=2 members gathers its
// members' pixel keys and overwrites its own slot with the region key.
// Member sets are disjoint -> race-free. Singletons already hold region key.
__global__ __launch_bounds__(256) void k_reduce(const int* __restrict__ cnt,
                                                const int* __restrict__ mem,
                                                u64* __restrict__ bnkey, int total) {
  int idx = swz_idx();
  if (idx >= total) return;
  int c = cnt[idx];
  if (c < 2) return;
  int base = idx & ~(NPIX - 1);
  const int* mp = mem + ((size_t)idx << 4);
  u64 K = 0;
  for (int j = 0; j < c; ++j) K = umax64(K, bnkey[base + mp[j]]);
  bnkey[idx] = K;
}

// scan: coalesced per-slot mutual-best test. Min-side reps of mutual pairs
// append a packed (idx, c, v) entry to the worklist. The atomicAdd is
// wave-aggregated by the compiler (one atomic per wave). Entry order is
// nondeterministic but pair processing is order-independent (perfect
// matching -> all writes exclusive).
template<bool LVL0>
__global__ __launch_bounds__(256) void k_scan(const int* __restrict__ cnt,
                                              const u64* __restrict__ bnkey,
                                              u64* __restrict__ wl,
                                              int* __restrict__ ctr, int total) {
  int idx = swz_idx();
  if (idx >= total) return;
  int n = idx & (NPIX - 1);
  int base = idx - n;
  int c = 1;
  if (!LVL0) { c = cnt[idx]; if (c <= 0) return; }
  u64 K = bnkey[idx];
  int v = NPIX - (int)(K & 0xffffffffu);   // K==0 -> v==NPIX
  if (v >= NPIX) return;
  if (n > v) return;                        // only the min side acts
  u64 Kv = bnkey[base + v];
  if (NPIX - (int)(Kv & 0xffffffffu) != n) return;   // not mutual
  int pos = atomicAdd(ctr, 1);
  wl[pos] = ((u64)(u32)idx << 32) | ((u64)(u32)c << 18) | (u32)v;
}

// compacted pair processing: dense waves over only the real merge pairs.
// Register-only streaming two-pointer merges (no runtime-indexed local
// arrays -> no scratch):
//   ascending pass: bit-exact ascending-pixel-order f32 sums + label scatter
//   descending pass: in-place merged-list write into the rep's mem slot.
//     Write index t2 = i2+j2+1 >= i2, and the read ma[i2] happens before the
//     write each iteration, so no unread own-list entry is ever clobbered.
template<bool LVL0>
__global__ __launch_bounds__(256) void k_pairs(int* __restrict__ labels,
                                               int* __restrict__ cnt,
                                               int* __restrict__ mem,
                                               const u64* __restrict__ wl,
                                               const int* __restrict__ ctr,
                                               const float4* __restrict__ pix4,
                                               float4* __restrict__ mcol4) {
  int t = blockIdx.x * 256 + (int)threadIdx.x;
  if (t >= *ctr) return;
  u64 e = wl[t];
  int idx = (int)(e >> 32);
  int v = (int)(e & 0x3ffffu);
  int n = idx & (NPIX - 1);
  int base = idx - n;
  float s0, s1, s2, sg;
  int k;
  int* mo = mem + ((size_t)idx << 4);
  if (LVL0) {
    k = 2;
    float4 pa = pix4[idx];
    float4 pb = pix4[base + v];
    s0 = __fadd_rn(__fadd_rn(0.f, pa.x), pb.x);
    s1 = __fadd_rn(__fadd_rn(0.f, pa.y), pb.y);
    s2 = __fadd_rn(__fadd_rn(0.f, pa.z), pb.z);
    sg = __fadd_rn(__fadd_rn(0.f, pa.w), pb.w);
    mo[0] = n; mo[1] = v;
    labels[idx] = n;
    labels[base + v] = n;
  } else {
    int c = (int)((e >> 18) & 0x1fu);
    int cb = cnt[base + v];
    const int* ma = mem + ((size_t)idx << 4);
    const int* mb = mem + ((size_t)(base + v) << 4);
    k = c + cb;
    s0 = s1 = s2 = sg = 0.f;
    int i = 0, j = 0;
    while (i < c || j < cb) {
      int av = (i < c) ? ((c == 1) ? n : ma[i]) : 0x7fffffff;
      int bv = (j < cb) ? ((cb == 1) ? v : mb[j]) : 0x7fffffff;
      int x;
      if (av < bv) { x = av; ++i; } else { x = bv; ++j; }
      float4 p = pix4[base + x];
      s0 = __fadd_rn(s0, p.x);
      s1 = __fadd_rn(s1, p.y);
      s2 = __fadd_rn(s2, p.z);
      sg = __fadd_rn(sg, p.w);
      labels[base + x] = n;
    }
    int i2 = c - 1, j2 = cb - 1;
    for (int t2 = k - 1; t2 >= 0; --t2) {
      int av = (i2 >= 0) ? ((c == 1) ? n : ma[i2]) : (int)0x80000000;
      int bv = (j2 >= 0) ? ((cb == 1) ? v : mb[j2]) : (int)0x80000000;
      int x;
      if (av > bv) { x = av; --i2; } else { x = bv; --j2; }
      mo[t2] = x;
    }
  }
  float safe = (float)k;
  mcol4[idx] = make_float4(__fdiv_rn(s0, safe), __fdiv_rn(s1, safe),
                           __fdiv_rn(s2, safe), __fdiv_rn(sg, safe));
  cnt[idx] = k;
  cnt[base + v] = 0;
}

// write labels (as f32) + region-mean color map
__global__ __launch_bounds__(256) void k_out(const int* __restrict__ labels,
                                             const float4* __restrict__ mcol4,
                                             float* __restrict__ out, int total,
                                             int b0, int Btot) {
  int idx = swz_idx();
  if (idx >= total) return;
  int b = idx >> NSH;
  int n = idx & (NPIX - 1);
  int l = labels[idx];
  out[(size_t)(b0 + b) * NPIX + n] = (float)l;
  size_t cb = (size_t)Btot * NPIX;
  float4 m = mcol4[(size_t)(b << NSH) + l];
  out[cb + ((size_t)(b0 + b) * 3 + 0) * NPIX + n] = m.x;
  out[cb + ((size_t)(b0 + b) * 3 + 1) * NPIX + n] = m.y;
  out[cb + ((size_t)(b0 + b) * 3 + 2) * NPIX + n] = m.z;
}

extern "C" void kernel_launch(void* const* d_in, const int* in_sizes, int n_in,
                              void* d_out, int out_size, void* d_ws, size_t ws_size,
                              hipStream_t stream) {
  const float* feat = (const float*)d_in[0];
  float* out = (float*)d_out;
  int Btot = in_sizes[0] / (3 * NPIX);

  int* ctr = (int*)d_ws;                  // 8 worklist counters, 256B reserved
  char* wsb = (char*)d_ws + 256;
  // per-pixel ws bytes: mcol4 16 + pix4 16 + bnkey 8 + wl 4 + labels 4 + cnt 4 + mem 64 = 116
  const size_t perB = (size_t)NPIX * 116;
  size_t avail = (ws_size > 256) ? (ws_size - 256) : 0;
  int nbmax = (int)(avail / perB);
  if (nbmax < 1) nbmax = 1;
  if (nbmax > Btot) nbmax = Btot;

  for (int b0 = 0; b0 < Btot; b0 += nbmax) {
    int nb = (Btot - b0 < nbmax) ? (Btot - b0) : nbmax;
    size_t cn = (size_t)nb << NSH;
    char* p = wsb;
    float4* mcol4 = (float4*)p; p += cn * 16;   // 16B-aligned first
    float4* pix4 = (float4*)p;  p += cn * 16;
    u64* bnkey = (u64*)p;       p += cn * 8;
    u64* wl = (u64*)p;          p += cn * 4;    // cn/2 entries x 8B (max pairs)
    int* labels = (int*)p;      p += cn * 4;
    int* cnt = (int*)p;         p += cn * 4;
    int* mem = (int*)p;

    const float* fchunk = feat + (size_t)b0 * 3 * NPIX;
    int total = (int)cn;
    int grid = total >> 8;    // nb*1024 blocks, divisible by 8 (swizzle req.)
    int gridp = total >> 9;   // pair kernel worst case: total/2 pairs

    k_prep0<<<grid, 256, 0, stream>>>(fchunk, labels, cnt, pix4, mcol4, bnkey, ctr, total);
    k_scan<true><<<grid, 256, 0, stream>>>(cnt, bnkey, wl, ctr + 0, total);
    k_pairs<true><<<gridp, 256, 0, stream>>>(labels, cnt, mem, wl, ctr + 0, pix4, mcol4);
    for (int lvl = 1; lvl < 4; ++lvl) {
      k_pixedge<<<grid, 256, 0, stream>>>(labels, mcol4, bnkey, total);
      k_reduce<<<grid, 256, 0, stream>>>(cnt, mem, bnkey, total);
      k_scan<false><<<grid, 256, 0, stream>>>(cnt, bnkey, wl, ctr + lvl, total);
      k_pairs<false><<<gridp, 256, 0, stream>>>(labels, cnt, mem, wl, ctr + lvl, pix4, mcol4);
    }
    k_out<<<grid, 256, 0, stream>>>(labels, mcol4, out, total, b0, Btot);
  }
}

// Round 2
// 322.365 us; speedup vs baseline: 5.9476x; 5.9476x over previous
//
#include <hip/hip_runtime.h>
#include <math.h>

#define WW 512
#define HH 512
#define NPIX (WW*HH)
#define NSH 18  /* log2(NPIX) */
#define NXCD 8

typedef unsigned long long u64;
typedef unsigned int u32;

__device__ __forceinline__ u64 umax64(u64 a, u64 b) { return a > b ? a : b; }

// XCD-contiguous block remap. Grid (=total/256) is always nb*1024 -> divisible
// by 8, so this is a bijection. Each XCD gets a contiguous slab of pixel slots
// (at nb=8: exactly one image per XCD) so neighbor-indexed reads hit the
// issuing XCD's own L2 instead of being re-fetched by all 8 private L2s.
__device__ __forceinline__ int swz_idx() {
  int g = gridDim.x;                       // multiple of 8 by construction
  int b = (int)blockIdx.x;
  int nb2 = (b & (NXCD - 1)) * (g >> 3) + (b >> 3);
  return nb2 * 256 + (int)threadIdx.x;
}

// colors + gradient magnitude of pixel p (same __f*_rn sequence as always ->
// bit-identical to the reference's XLA lowering)
__device__ __forceinline__ float d_colg(const float* __restrict__ fb, int p, int pw, int ph,
                                        float col[3]) {
  float s = 0.f;
#pragma unroll
  for (int c = 0; c < 3; ++c) {
    const float* fc = fb + (size_t)c * NPIX;
    float v = fc[p];
    col[c] = v;
    float gx = (pw < WW - 1) ? __fsub_rn(fc[p + 1], v) : 0.f;
    float gy = (ph < HH - 1) ? __fsub_rn(fc[p + WW], v) : 0.f;
    float g = __fsqrt_rn(__fadd_rn(__fadd_rn(__fmul_rn(gx, gx), __fmul_rn(gy, gy)), 1e-12f));
    s = __fadd_rn(s, g);
  }
  return __fdiv_rn(s, 3.0f);
}

// packed key: (sim_bits<<32) | (NPIX-lb). max == {segment_max sim, then
// segment_min of tied neighbor labels}: sim>0 so bits are monotone; among
// sim-ties, max of NPIX-lb picks min lb. Bitwise symmetric in (a,b).
__device__ __forceinline__ u64 d_simkey(float a0, float a1, float a2, float ag,
                                        float b0, float b1, float b2, float bg, int lb) {
  float d0 = __fsub_rn(a0, b0);
  float d1 = __fsub_rn(a1, b1);
  float d2 = __fsub_rn(a2, b2);
  float ss = __fadd_rn(__fadd_rn(__fmul_rn(d0, d0), __fmul_rn(d1, d1)), __fmul_rn(d2, d2));
  float dc = __fsqrt_rn(__fadd_rn(ss, 1e-12f));
  float ge = __fmul_rn(0.5f, __fadd_rn(ag, bg));
  float t = __fadd_rn(__fdiv_rn(dc, 10.0f), __fdiv_rn(ge, 27.8f));
  float sim = (float)exp(-(double)t);   // ~correctly-rounded expf
  return ((u64)__float_as_uint(sim) << 32) | (u32)(NPIX - lb);
}

// fused prep + level-0 edge pass: per-pixel state (labels/cnt/pix4/mcol4) and
// the level-0 packed key over all 4 directed edges (labels are identity, so
// every neighbor is a distinct region; neighbor means = pixel values,
// recomputed inline with the identical instruction sequence).
__global__ __launch_bounds__(256) void k_prep0(const float* __restrict__ feat,
                                               int* __restrict__ labels,
                                               int* __restrict__ cnt,
                                               float4* __restrict__ pix4,
                                               float4* __restrict__ mcol4,
                                               u64* __restrict__ bnkey, int total) {
  int idx = swz_idx();
  if (idx >= total) return;
  int b = idx >> NSH;
  int n = idx & (NPIX - 1);
  int w = n & (WW - 1);
  int h = n >> 9;
  const float* fb = feat + (size_t)b * 3 * NPIX;
  float ca[3];
  float ga = d_colg(fb, n, w, h, ca);
  labels[idx] = n;
  cnt[idx] = 1;
  float4 p4 = make_float4(ca[0], ca[1], ca[2], ga);
  pix4[idx] = p4;
  mcol4[idx] = p4;   // level-0 region mean == pixel (exact: x/1.0)
  u64 key = 0;
#pragma unroll
  for (int d = 0; d < 4; ++d) {
    bool ok; int q, qw, qh;
    switch (d) {
      case 0: ok = (w < WW - 1); q = n + 1;  qw = w + 1; qh = h;     break;
      case 1: ok = (w > 0);      q = n - 1;  qw = w - 1; qh = h;     break;
      case 2: ok = (h < HH - 1); q = n + WW; qw = w;     qh = h + 1; break;
      default: ok = (h > 0);     q = n - WW; qw = w;     qh = h - 1; break;
    }
    if (!ok) continue;
    float cb[3];
    float gb = d_colg(fb, q, qw, qh, cb);
    key = umax64(key, d_simkey(ca[0], ca[1], ca[2], ga, cb[0], cb[1], cb[2], gb, q));
  }
  bnkey[idx] = key;
}

// levels >=1: per-pixel edge pass. Each pixel max-reduces the packed keys of
// its own <=4 directed edges in registers and writes ONE coalesced u64.
__global__ __launch_bounds__(256) void k_pixedge(const int* __restrict__ labels,
                                                 const float4* __restrict__ mcol4,
                                                 u64* __restrict__ bnkey, int total) {
  int idx = swz_idx();
  if (idx >= total) return;
  int n = idx & (NPIX - 1);
  int base = idx - n;
  int w = n & (WW - 1);
  int h = n >> 9;
  int la = labels[idx];
  float4 ma = mcol4[base + la];
  u64 key = 0;
  int seen0 = -1, seen1 = -1, seen2 = -1;
#pragma unroll
  for (int d = 0; d < 4; ++d) {
    bool ok; int q;
    switch (d) {
      case 0: ok = (w < WW - 1); q = n + 1;  break;
      case 1: ok = (w > 0);      q = n - 1;  break;
      case 2: ok = (h < HH - 1); q = n + WW; break;
      default: ok = (h > 0);     q = n - WW; break;
    }
    if (!ok) continue;
    int lb = labels[base + q];
    if (lb == la || lb == seen0 || lb == seen1 || lb == seen2) continue;
    seen2 = seen1; seen1 = seen0; seen0 = lb;
    float4 mb = mcol4[base + lb];
    key = umax64(key, d_simkey(ma.x, ma.y, ma.z, ma.w, mb.x, mb.y, mb.z, mb.w, lb));
  }
  bnkey[idx] = key;
}

// in-place region reduction: each live rep with >=2 members gathers its
// members' pixel keys and overwrites its own slot with the region key.
// Member sets are disjoint -> race-free. Singletons already hold region key.
__global__ __launch_bounds__(256) void k_reduce(const int* __restrict__ cnt,
                                                const int* __restrict__ mem,
                                                u64* __restrict__ bnkey, int total) {
  int idx = swz_idx();
  if (idx >= total) return;
  int c = cnt[idx];
  if (c < 2) return;
  int base = idx & ~(NPIX - 1);
  const int* mp = mem + ((size_t)idx << 4);
  u64 K = 0;
  for (int j = 0; j < c; ++j) K = umax64(K, bnkey[base + mp[j]]);
  bnkey[idx] = K;
}

// fused scan + pair processing with LDS-level compaction (no global atomics,
// no global worklist). Phase 1: each block tests the mutual-best predicate for
// its own 256 slots (coalesced bnkey read + one neighbor-key gather) and
// compacts the pair entries into LDS via ballot prefix + one LDS atomic per
// wave. Phase 2: threads 0..m-1 process the pairs with dense front waves --
// the heavy merge body runs at full lane utilization; empty tail waves exit.
//
// Fusion safety: phase-1 reads only bnkey (never written here) and cnt. The
// only cross-block overlap is phase-2 writing cnt[partner]=0 while the
// partner's own block phase-1-reads it; either value leads to "contributes
// nothing" (the partner fails the n>v min-side test). All phase-2 writes
// (labels/mem/mcol4/cnt) are exclusive under the mutual-best perfect matching.
//
// Merge body: register-only streaming two-pointer merges (no runtime-indexed
// local arrays -> no scratch):
//   ascending pass: bit-exact ascending-pixel-order f32 sums + label scatter
//   descending pass: in-place merged-list write into the rep's mem slot.
//     Write index t2 = i2+j2+1 >= i2, and the read ma[i2] happens before the
//     write each iteration, so no unread own-list entry is ever clobbered.
template<bool LVL0>
__global__ __launch_bounds__(256) void k_scanpairs(int* __restrict__ labels,
                                                   int* __restrict__ cnt,
                                                   int* __restrict__ mem,
                                                   const u64* __restrict__ bnkey,
                                                   const float4* __restrict__ pix4,
                                                   float4* __restrict__ mcol4, int total) {
  __shared__ u64 swl[256];
  __shared__ int scnt;
  if (threadIdx.x == 0) scnt = 0;
  __syncthreads();

  int idx = swz_idx();
  bool pred = false;
  u64 e = 0;
  if (idx < total) {
    int n = idx & (NPIX - 1);
    int base = idx - n;
    int c = 1;
    bool live = true;
    if (!LVL0) { c = cnt[idx]; live = (c > 0); }
    if (live) {
      u64 K = bnkey[idx];
      int v = NPIX - (int)(K & 0xffffffffu);   // K==0 -> v==NPIX
      if (v < NPIX && n < v) {                  // only the min side acts
        u64 Kv = bnkey[base + v];
        if (NPIX - (int)(Kv & 0xffffffffu) == n) {   // mutual
          pred = true;
          e = ((u64)(u32)idx << 32) | ((u64)(u32)c << 18) | (u32)v;
        }
      }
    }
  }

  // LDS compaction: ballot prefix within wave, one LDS atomic per wave.
  u64 mask = __ballot(pred);
  int lane = (int)(threadIdx.x & 63);
  int wb0 = 0;
  if (lane == 0 && mask) wb0 = atomicAdd(&scnt, __popcll(mask));
  int wb = __shfl(wb0, 0);
  if (pred) {
    int pos = wb + __popcll(mask & ((1ull << lane) - 1ull));
    swl[pos] = e;
  }
  __syncthreads();
  int m = scnt;
  if ((int)threadIdx.x >= m) return;

  e = swl[threadIdx.x];
  int idx2 = (int)(e >> 32);
  int v = (int)(e & 0x3ffffu);
  int n = idx2 & (NPIX - 1);
  int base = idx2 - n;
  float s0, s1, s2, sg;
  int k;
  int* mo = mem + ((size_t)idx2 << 4);
  if (LVL0) {
    k = 2;
    float4 pa = pix4[idx2];
    float4 pb = pix4[base + v];
    s0 = __fadd_rn(__fadd_rn(0.f, pa.x), pb.x);
    s1 = __fadd_rn(__fadd_rn(0.f, pa.y), pb.y);
    s2 = __fadd_rn(__fadd_rn(0.f, pa.z), pb.z);
    sg = __fadd_rn(__fadd_rn(0.f, pa.w), pb.w);
    mo[0] = n; mo[1] = v;
    labels[idx2] = n;
    labels[base + v] = n;
  } else {
    int c = (int)((e >> 18) & 0x1fu);
    int cb = cnt[base + v];
    const int* ma = mem + ((size_t)idx2 << 4);
    const int* mb = mem + ((size_t)(base + v) << 4);
    k = c + cb;
    s0 = s1 = s2 = sg = 0.f;
    int i = 0, j = 0;
    while (i < c || j < cb) {
      int av = (i < c) ? ((c == 1) ? n : ma[i]) : 0x7fffffff;
      int bv = (j < cb) ? ((cb == 1) ? v : mb[j]) : 0x7fffffff;
      int x;
      if (av < bv) { x = av; ++i; } else { x = bv; ++j; }
      float4 p = pix4[base + x];
      s0 = __fadd_rn(s0, p.x);
      s1 = __fadd_rn(s1, p.y);
      s2 = __fadd_rn(s2, p.z);
      sg = __fadd_rn(sg, p.w);
      labels[base + x] = n;
    }
    int i2 = c - 1, j2 = cb - 1;
    for (int t2 = k - 1; t2 >= 0; --t2) {
      int av = (i2 >= 0) ? ((c == 1) ? n : ma[i2]) : (int)0x80000000;
      int bv = (j2 >= 0) ? ((cb == 1) ? v : mb[j2]) : (int)0x80000000;
      int x;
      if (av > bv) { x = av; --i2; } else { x = bv; --j2; }
      mo[t2] = x;
    }
  }
  float safe = (float)k;
  mcol4[idx2] = make_float4(__fdiv_rn(s0, safe), __fdiv_rn(s1, safe),
                            __fdiv_rn(s2, safe), __fdiv_rn(sg, safe));
  cnt[idx2] = k;
  cnt[base + v] = 0;
}

// write labels (as f32) + region-mean color map
__global__ __launch_bounds__(256) void k_out(const int* __restrict__ labels,
                                             const float4* __restrict__ mcol4,
                                             float* __restrict__ out, int total,
                                             int b0, int Btot) {
  int idx = swz_idx();
  if (idx >= total) return;
  int b = idx >> NSH;
  int n = idx & (NPIX - 1);
  int l = labels[idx];
  out[(size_t)(b0 + b) * NPIX + n] = (float)l;
  size_t cb = (size_t)Btot * NPIX;
  float4 m = mcol4[(size_t)(b << NSH) + l];
  out[cb + ((size_t)(b0 + b) * 3 + 0) * NPIX + n] = m.x;
  out[cb + ((size_t)(b0 + b) * 3 + 1) * NPIX + n] = m.y;
  out[cb + ((size_t)(b0 + b) * 3 + 2) * NPIX + n] = m.z;
}

extern "C" void kernel_launch(void* const* d_in, const int* in_sizes, int n_in,
                              void* d_out, int out_size, void* d_ws, size_t ws_size,
                              hipStream_t stream) {
  const float* feat = (const float*)d_in[0];
  float* out = (float*)d_out;
  int Btot = in_sizes[0] / (3 * NPIX);

  // per-pixel ws bytes: mcol4 16 + pix4 16 + bnkey 8 + labels 4 + cnt 4 + mem 64 = 112
  const size_t perB = (size_t)NPIX * 112;
  int nbmax = (int)(ws_size / perB);
  if (nbmax < 1) nbmax = 1;
  if (nbmax > Btot) nbmax = Btot;

  for (int b0 = 0; b0 < Btot; b0 += nbmax) {
    int nb = (Btot - b0 < nbmax) ? (Btot - b0) : nbmax;
    size_t cn = (size_t)nb << NSH;
    char* p = (char*)d_ws;
    float4* mcol4 = (float4*)p; p += cn * 16;   // 16B-aligned first
    float4* pix4 = (float4*)p;  p += cn * 16;
    u64* bnkey = (u64*)p;       p += cn * 8;
    int* labels = (int*)p;      p += cn * 4;
    int* cnt = (int*)p;         p += cn * 4;
    int* mem = (int*)p;

    const float* fchunk = feat + (size_t)b0 * 3 * NPIX;
    int total = (int)cn;
    int grid = total >> 8;    // nb*1024 blocks, divisible by 8 (swizzle req.)

    k_prep0<<<grid, 256, 0, stream>>>(fchunk, labels, cnt, pix4, mcol4, bnkey, total);
    k_scanpairs<true><<<grid, 256, 0, stream>>>(labels, cnt, mem, bnkey, pix4, mcol4, total);
    for (int lvl = 1; lvl < 4; ++lvl) {
      k_pixedge<<<grid, 256, 0, stream>>>(labels, mcol4, bnkey, total);
      k_reduce<<<grid, 256, 0, stream>>>(cnt, mem, bnkey, total);
      k_scanpairs<false><<<grid, 256, 0, stream>>>(labels, cnt, mem, bnkey, pix4, mcol4, total);
    }
    k_out<<<grid, 256, 0, stream>>>(labels, mcol4, out, total, b0, Btot);
  }
}

// Round 3
// 314.522 us; speedup vs baseline: 6.0959x; 1.0249x over previous
//
#include <hip/hip_runtime.h>
#include <math.h>

#define WW 512
#define HH 512
#define NPIX (WW*HH)
#define NSH 18  /* log2(NPIX) */
#define NXCD 8

typedef unsigned long long u64;
typedef unsigned int u32;

__device__ __forceinline__ u64 umax64(u64 a, u64 b) { return a > b ? a : b; }

// XCD-contiguous block remap for the 1-D kernels (reduce/scanpairs/out).
// Grid is always nb*1024 -> divisible by 8, so this is a bijection. Each XCD
// gets a contiguous slab of pixel slots (at nb=8: one image per XCD) so
// neighbor-indexed reads hit the issuing XCD's own L2.
__device__ __forceinline__ int swz_idx() {
  int g = gridDim.x;
  int b = (int)blockIdx.x;
  int nb2 = (b & (NXCD - 1)) * (g >> 3) + (b >> 3);
  return nb2 * 256 + (int)threadIdx.x;
}

// Tile mapping for the 2-D edge kernels: 32x8-pixel tiles, 16x64 tiles per
// image, XCD-slab swizzled the same way (t contiguous per XCD; at nb=8 each
// XCD owns one image, so vertically adjacent tiles share halo in one L2).
__device__ __forceinline__ void tile_coords(int& bb, int& x0, int& y0) {
  int g = gridDim.x;
  int b = (int)blockIdx.x;
  int t = (b & (NXCD - 1)) * (g >> 3) + (b >> 3);
  bb = t >> 10;
  int rem = t & 1023;
  y0 = (rem >> 4) << 3;   // tile row * 8
  x0 = (rem & 15) << 5;   // tile col * 32
}

// colors + gradient magnitude of pixel p (same __f*_rn sequence as always ->
// bit-identical to the reference's XLA lowering)
__device__ __forceinline__ float d_colg(const float* __restrict__ fb, int p, int pw, int ph,
                                        float col[3]) {
  float s = 0.f;
#pragma unroll
  for (int c = 0; c < 3; ++c) {
    const float* fc = fb + (size_t)c * NPIX;
    float v = fc[p];
    col[c] = v;
    float gx = (pw < WW - 1) ? __fsub_rn(fc[p + 1], v) : 0.f;
    float gy = (ph < HH - 1) ? __fsub_rn(fc[p + WW], v) : 0.f;
    float g = __fsqrt_rn(__fadd_rn(__fadd_rn(__fmul_rn(gx, gx), __fmul_rn(gy, gy)), 1e-12f));
    s = __fadd_rn(s, g);
  }
  return __fdiv_rn(s, 3.0f);
}

// sim bits (<<32) for the undirected edge between means a and b. Bitwise
// symmetric: d and -d square identically, fadd is commutative -> ONE exp
// serves both endpoints; only the tiebreak low word (NPIX-lb) is per-side.
// Instruction sequence identical to the original d_simkey.
__device__ __forceinline__ u64 d_simbits(float4 a, float4 b) {
  float d0 = __fsub_rn(a.x, b.x);
  float d1 = __fsub_rn(a.y, b.y);
  float d2 = __fsub_rn(a.z, b.z);
  float ss = __fadd_rn(__fadd_rn(__fmul_rn(d0, d0), __fmul_rn(d1, d1)), __fmul_rn(d2, d2));
  float dc = __fsqrt_rn(__fadd_rn(ss, 1e-12f));
  float ge = __fmul_rn(0.5f, __fadd_rn(a.w, b.w));
  float t = __fadd_rn(__fdiv_rn(dc, 10.0f), __fdiv_rn(ge, 27.8f));
  float sim = (float)exp(-(double)t);   // ~correctly-rounded expf
  return ((u64)__float_as_uint(sim)) << 32;
}

// fused prep + level-0 edge pass, tiled. Phase 1: the 34x10 colg halo region
// is computed ONCE per cell into LDS (1.33 colg/pixel vs 5 before). Phase 2:
// each internal undirected edge computes sim ONCE (2.16 exps/pixel vs 4);
// own-side contribution merges in registers, partner side via LDS atomicMax.
// Boundary edges (partner in neighboring tile) are computed solo from the
// LDS halo. Identity labels -> every neighbor is a distinct region.
__global__ __launch_bounds__(256) void k_prep0edge(const float* __restrict__ feat,
                                                   int* __restrict__ labels,
                                                   int* __restrict__ cnt,
                                                   float4* __restrict__ pix4,
                                                   float4* __restrict__ mcol4,
                                                   u64* __restrict__ bnkey) {
  __shared__ float4 scolg[340];   // 34 x 10 halo region
  __shared__ u64 skey[256];
  int bb, x0, y0;
  tile_coords(bb, x0, y0);
  const float* fb = feat + (size_t)bb * 3 * NPIX;
  int tid = (int)threadIdx.x;
  skey[tid] = 0;
  for (int c = tid; c < 340; c += 256) {
    int cx = (c % 34) - 1, cy = (c / 34) - 1;
    int x = x0 + cx, y = y0 + cy;
    if (x >= 0 && x < WW && y >= 0 && y < HH) {
      float col[3];
      float g = d_colg(fb, y * WW + x, x, y, col);
      scolg[c] = make_float4(col[0], col[1], col[2], g);
    }
  }
  __syncthreads();
  int tx = tid & 31, ty = tid >> 5;
  int x = x0 + tx, y = y0 + ty;
  int n = y * WW + x;
  int idx = (bb << NSH) + n;
  int cell = (ty + 1) * 34 + (tx + 1);
  float4 ca = scolg[cell];
  labels[idx] = n;
  cnt[idx] = 1;
  pix4[idx] = ca;
  mcol4[idx] = ca;   // level-0 region mean == pixel (exact: x/1.0)
  u64 key = 0;
  if (x < WW - 1) {              // right edge
    u64 s = d_simbits(ca, scolg[cell + 1]);
    key = umax64(key, s | (u32)(NPIX - (n + 1)));
    if (tx < 31) atomicMax(&skey[tid + 1], s | (u32)(NPIX - n));
  }
  if (tx == 0 && x > 0) {        // left boundary edge (solo)
    u64 s = d_simbits(ca, scolg[cell - 1]);
    key = umax64(key, s | (u32)(NPIX - (n - 1)));
  }
  if (y < HH - 1) {              // down edge
    u64 s = d_simbits(ca, scolg[cell + 34]);
    key = umax64(key, s | (u32)(NPIX - (n + WW)));
    if (ty < 7) atomicMax(&skey[tid + 32], s | (u32)(NPIX - n));
  }
  if (ty == 0 && y > 0) {        // up boundary edge (solo)
    u64 s = d_simbits(ca, scolg[cell - 34]);
    key = umax64(key, s | (u32)(NPIX - (n - WW)));
  }
  __syncthreads();
  bnkey[idx] = umax64(key, skey[tid]);
}

// levels >=1 edge pass, tiled with shared sims. (la, ma) staged in LDS for
// the 256 core pixels; internal inter-region edges compute sim once and
// distribute both endpoint keys (register for self, LDS atomicMax for
// partner). Boundary edges read the neighbor's label/mean from global
// (L2-cached) and contribute solo. Duplicate-region edges recompute the same
// sim (same bits) -> max unaffected, correctness preserved.
__global__ __launch_bounds__(256) void k_edge(const int* __restrict__ labels,
                                              const float4* __restrict__ mcol4,
                                              u64* __restrict__ bnkey) {
  __shared__ int sla[256];
  __shared__ float4 sma[256];
  __shared__ u64 skey[256];
  int bb, x0, y0;
  tile_coords(bb, x0, y0);
  int tid = (int)threadIdx.x;
  int tx = tid & 31, ty = tid >> 5;
  int x = x0 + tx, y = y0 + ty;
  int n = y * WW + x;
  int base = bb << NSH;
  int idx = base + n;
  int la = labels[idx];
  float4 ma = mcol4[base + la];
  sla[tid] = la;
  sma[tid] = ma;
  skey[tid] = 0;
  __syncthreads();
  u64 key = 0;
  if (x < WW - 1) {              // right edge
    if (tx < 31) {
      int lb = sla[tid + 1];
      if (lb != la) {
        u64 s = d_simbits(ma, sma[tid + 1]);
        key = umax64(key, s | (u32)(NPIX - lb));
        atomicMax(&skey[tid + 1], s | (u32)(NPIX - la));
      }
    } else {
      int lb = labels[idx + 1];
      if (lb != la) key = umax64(key, d_simbits(ma, mcol4[base + lb]) | (u32)(NPIX - lb));
    }
  }
  if (tx == 0 && x > 0) {        // left boundary edge (solo)
    int lb = labels[idx - 1];
    if (lb != la) key = umax64(key, d_simbits(ma, mcol4[base + lb]) | (u32)(NPIX - lb));
  }
  if (y < HH - 1) {              // down edge
    if (ty < 7) {
      int lb = sla[tid + 32];
      if (lb != la) {
        u64 s = d_simbits(ma, sma[tid + 32]);
        key = umax64(key, s | (u32)(NPIX - lb));
        atomicMax(&skey[tid + 32], s | (u32)(NPIX - la));
      }
    } else {
      int lb = labels[idx + WW];
      if (lb != la) key = umax64(key, d_simbits(ma, mcol4[base + lb]) | (u32)(NPIX - lb));
    }
  }
  if (ty == 0 && y > 0) {        // up boundary edge (solo)
    int lb = labels[idx - WW];
    if (lb != la) key = umax64(key, d_simbits(ma, mcol4[base + lb]) | (u32)(NPIX - lb));
  }
  __syncthreads();
  bnkey[idx] = umax64(key, skey[tid]);
}

// in-place region reduction: each live rep with >=2 members gathers its
// members' pixel keys and overwrites its own slot with the region key.
// Member sets are disjoint -> race-free. Singletons already hold region key.
__global__ __launch_bounds__(256) void k_reduce(const int* __restrict__ cnt,
                                                const int* __restrict__ mem,
                                                u64* __restrict__ bnkey, int total) {
  int idx = swz_idx();
  if (idx >= total) return;
  int c = cnt[idx];
  if (c < 2) return;
  int base = idx & ~(NPIX - 1);
  const int* mp = mem + ((size_t)idx << 4);
  u64 K = 0;
  for (int j = 0; j < c; ++j) K = umax64(K, bnkey[base + mp[j]]);
  bnkey[idx] = K;
}

// fused scan + pair processing with LDS-level compaction (no global atomics,
// no global worklist). Phase 1: mutual-best predicate for the block's 256
// slots, compacted into LDS via ballot prefix + one LDS atomic per wave.
// Phase 2: threads 0..m-1 process the pairs with dense front waves.
// Fusion safety & merge-body notes: see round-2 version (unchanged).
template<bool LVL0>
__global__ __launch_bounds__(256) void k_scanpairs(int* __restrict__ labels,
                                                   int* __restrict__ cnt,
                                                   int* __restrict__ mem,
                                                   const u64* __restrict__ bnkey,
                                                   const float4* __restrict__ pix4,
                                                   float4* __restrict__ mcol4, int total) {
  __shared__ u64 swl[256];
  __shared__ int scnt;
  if (threadIdx.x == 0) scnt = 0;
  __syncthreads();

  int idx = swz_idx();
  bool pred = false;
  u64 e = 0;
  if (idx < total) {
    int n = idx & (NPIX - 1);
    int base = idx - n;
    int c = 1;
    bool live = true;
    if (!LVL0) { c = cnt[idx]; live = (c > 0); }
    if (live) {
      u64 K = bnkey[idx];
      int v = NPIX - (int)(K & 0xffffffffu);   // K==0 -> v==NPIX
      if (v < NPIX && n < v) {                  // only the min side acts
        u64 Kv = bnkey[base + v];
        if (NPIX - (int)(Kv & 0xffffffffu) == n) {   // mutual
          pred = true;
          e = ((u64)(u32)idx << 32) | ((u64)(u32)c << 18) | (u32)v;
        }
      }
    }
  }

  u64 mask = __ballot(pred);
  int lane = (int)(threadIdx.x & 63);
  int wb0 = 0;
  if (lane == 0 && mask) wb0 = atomicAdd(&scnt, __popcll(mask));
  int wb = __shfl(wb0, 0);
  if (pred) {
    int pos = wb + __popcll(mask & ((1ull << lane) - 1ull));
    swl[pos] = e;
  }
  __syncthreads();
  int m = scnt;
  if ((int)threadIdx.x >= m) return;

  e = swl[threadIdx.x];
  int idx2 = (int)(e >> 32);
  int v = (int)(e & 0x3ffffu);
  int n = idx2 & (NPIX - 1);
  int base = idx2 - n;
  float s0, s1, s2, sg;
  int k;
  int* mo = mem + ((size_t)idx2 << 4);
  if (LVL0) {
    k = 2;
    float4 pa = pix4[idx2];
    float4 pb = pix4[base + v];
    s0 = __fadd_rn(__fadd_rn(0.f, pa.x), pb.x);
    s1 = __fadd_rn(__fadd_rn(0.f, pa.y), pb.y);
    s2 = __fadd_rn(__fadd_rn(0.f, pa.z), pb.z);
    sg = __fadd_rn(__fadd_rn(0.f, pa.w), pb.w);
    mo[0] = n; mo[1] = v;
    labels[idx2] = n;
    labels[base + v] = n;
  } else {
    int c = (int)((e >> 18) & 0x1fu);
    int cb = cnt[base + v];
    const int* ma = mem + ((size_t)idx2 << 4);
    const int* mb = mem + ((size_t)(base + v) << 4);
    k = c + cb;
    s0 = s1 = s2 = sg = 0.f;
    int i = 0, j = 0;
    while (i < c || j < cb) {
      int av = (i < c) ? ((c == 1) ? n : ma[i]) : 0x7fffffff;
      int bv = (j < cb) ? ((cb == 1) ? v : mb[j]) : 0x7fffffff;
      int x;
      if (av < bv) { x = av; ++i; } else { x = bv; ++j; }
      float4 p = pix4[base + x];
      s0 = __fadd_rn(s0, p.x);
      s1 = __fadd_rn(s1, p.y);
      s2 = __fadd_rn(s2, p.z);
      sg = __fadd_rn(sg, p.w);
      labels[base + x] = n;
    }
    int i2 = c - 1, j2 = cb - 1;
    for (int t2 = k - 1; t2 >= 0; --t2) {
      int av = (i2 >= 0) ? ((c == 1) ? n : ma[i2]) : (int)0x80000000;
      int bv = (j2 >= 0) ? ((cb == 1) ? v : mb[j2]) : (int)0x80000000;
      int x;
      if (av > bv) { x = av; --i2; } else { x = bv; --j2; }
      mo[t2] = x;
    }
  }
  float safe = (float)k;
  mcol4[idx2] = make_float4(__fdiv_rn(s0, safe), __fdiv_rn(s1, safe),
                            __fdiv_rn(s2, safe), __fdiv_rn(sg, safe));
  cnt[idx2] = k;
  cnt[base + v] = 0;
}

// write labels (as f32) + region-mean color map
__global__ __launch_bounds__(256) void k_out(const int* __restrict__ labels,
                                             const float4* __restrict__ mcol4,
                                             float* __restrict__ out, int total,
                                             int b0, int Btot) {
  int idx = swz_idx();
  if (idx >= total) return;
  int b = idx >> NSH;
  int n = idx & (NPIX - 1);
  int l = labels[idx];
  out[(size_t)(b0 + b) * NPIX + n] = (float)l;
  size_t cb = (size_t)Btot * NPIX;
  float4 m = mcol4[(size_t)(b << NSH) + l];
  out[cb + ((size_t)(b0 + b) * 3 + 0) * NPIX + n] = m.x;
  out[cb + ((size_t)(b0 + b) * 3 + 1) * NPIX + n] = m.y;
  out[cb + ((size_t)(b0 + b) * 3 + 2) * NPIX + n] = m.z;
}

extern "C" void kernel_launch(void* const* d_in, const int* in_sizes, int n_in,
                              void* d_out, int out_size, void* d_ws, size_t ws_size,
                              hipStream_t stream) {
  const float* feat = (const float*)d_in[0];
  float* out = (float*)d_out;
  int Btot = in_sizes[0] / (3 * NPIX);

  // per-pixel ws bytes: mcol4 16 + pix4 16 + bnkey 8 + labels 4 + cnt 4 + mem 64 = 112
  const size_t perB = (size_t)NPIX * 112;
  int nbmax = (int)(ws_size / perB);
  if (nbmax < 1) nbmax = 1;
  if (nbmax > Btot) nbmax = Btot;

  for (int b0 = 0; b0 < Btot; b0 += nbmax) {
    int nb = (Btot - b0 < nbmax) ? (Btot - b0) : nbmax;
    size_t cn = (size_t)nb << NSH;
    char* p = (char*)d_ws;
    float4* mcol4 = (float4*)p; p += cn * 16;   // 16B-aligned first
    float4* pix4 = (float4*)p;  p += cn * 16;
    u64* bnkey = (u64*)p;       p += cn * 8;
    int* labels = (int*)p;      p += cn * 4;
    int* cnt = (int*)p;         p += cn * 4;
    int* mem = (int*)p;

    const float* fchunk = feat + (size_t)b0 * 3 * NPIX;
    int total = (int)cn;
    int grid = total >> 8;    // nb*1024 blocks, divisible by 8 (swizzle req.)

    k_prep0edge<<<grid, 256, 0, stream>>>(fchunk, labels, cnt, pix4, mcol4, bnkey);
    k_scanpairs<true><<<grid, 256, 0, stream>>>(labels, cnt, mem, bnkey, pix4, mcol4, total);
    for (int lvl = 1; lvl < 4; ++lvl) {
      k_edge<<<grid, 256, 0, stream>>>(labels, mcol4, bnkey);
      k_reduce<<<grid, 256, 0, stream>>>(cnt, mem, bnkey, total);
      k_scanpairs<false><<<grid, 256, 0, stream>>>(labels, cnt, mem, bnkey, pix4, mcol4, total);
    }
    k_out<<<grid, 256, 0, stream>>>(labels, mcol4, out, total, b0, Btot);
  }
}

// Round 4
// 305.888 us; speedup vs baseline: 6.2680x; 1.0282x over previous
//
#include <hip/hip_runtime.h>
#include <math.h>

#define WW 512
#define HH 512
#define NPIX (WW*HH)
#define NSH 18  /* log2(NPIX) */
#define NXCD 8

typedef unsigned long long u64;
typedef unsigned int u32;
typedef unsigned short u16;

__device__ __forceinline__ u64 umax64(u64 a, u64 b) { return a > b ? a : b; }

// XCD-contiguous block remap for the 1-D kernels (scanpairs/out).
// Grid is always nb*1024 -> divisible by 8, so this is a bijection. Each XCD
// gets a contiguous slab of pixel slots (at nb=8: one image per XCD) so
// neighbor-indexed reads hit the issuing XCD's own L2.
__device__ __forceinline__ int swz_idx() {
  int g = gridDim.x;
  int b = (int)blockIdx.x;
  int nb2 = (b & (NXCD - 1)) * (g >> 3) + (b >> 3);
  return nb2 * 256 + (int)threadIdx.x;
}

// Tile mapping for the 2-D edge kernels: 32x8-pixel tiles, 16x64 tiles per
// image, XCD-slab swizzled the same way (at nb=8 each XCD owns one image, so
// rep-slot atomics and halo reads stay in one XCD's L2).
__device__ __forceinline__ void tile_coords(int& bb, int& x0, int& y0) {
  int g = gridDim.x;
  int b = (int)blockIdx.x;
  int t = (b & (NXCD - 1)) * (g >> 3) + (b >> 3);
  bb = t >> 10;
  int rem = t & 1023;
  y0 = (rem >> 4) << 3;   // tile row * 8
  x0 = (rem & 15) << 5;   // tile col * 32
}

// colors + gradient magnitude of pixel p (same __f*_rn sequence as always ->
// bit-identical to the reference's XLA lowering)
__device__ __forceinline__ float d_colg(const float* __restrict__ fb, int p, int pw, int ph,
                                        float col[3]) {
  float s = 0.f;
#pragma unroll
  for (int c = 0; c < 3; ++c) {
    const float* fc = fb + (size_t)c * NPIX;
    float v = fc[p];
    col[c] = v;
    float gx = (pw < WW - 1) ? __fsub_rn(fc[p + 1], v) : 0.f;
    float gy = (ph < HH - 1) ? __fsub_rn(fc[p + WW], v) : 0.f;
    float g = __fsqrt_rn(__fadd_rn(__fadd_rn(__fmul_rn(gx, gx), __fmul_rn(gy, gy)), 1e-12f));
    s = __fadd_rn(s, g);
  }
  return __fdiv_rn(s, 3.0f);
}

// sim bits (<<32) for the undirected edge between means a and b. Bitwise
// symmetric -> ONE exp serves both endpoints; only the tiebreak low word
// (NPIX-lb) is per-side. Sequence identical to the original d_simkey.
__device__ __forceinline__ u64 d_simbits(float4 a, float4 b) {
  float d0 = __fsub_rn(a.x, b.x);
  float d1 = __fsub_rn(a.y, b.y);
  float d2 = __fsub_rn(a.z, b.z);
  float ss = __fadd_rn(__fadd_rn(__fmul_rn(d0, d0), __fmul_rn(d1, d1)), __fmul_rn(d2, d2));
  float dc = __fsqrt_rn(__fadd_rn(ss, 1e-12f));
  float ge = __fmul_rn(0.5f, __fadd_rn(a.w, b.w));
  float t = __fadd_rn(__fdiv_rn(dc, 10.0f), __fdiv_rn(ge, 27.8f));
  float sim = (float)exp(-(double)t);   // ~correctly-rounded expf
  return ((u64)__float_as_uint(sim)) << 32;
}

// fused prep + level-0 edge pass, tiled (unchanged from round 3). Writes the
// level-0 keys coalesced into buffer A (identity labels: every pixel is its
// own rep, so pixel slot == rep slot).
__global__ __launch_bounds__(256) void k_prep0edge(const float* __restrict__ feat,
                                                   int* __restrict__ labels,
                                                   int* __restrict__ cnt,
                                                   float4* __restrict__ pix4,
                                                   float4* __restrict__ mcol4,
                                                   u64* __restrict__ bnkey) {
  __shared__ float4 scolg[340];   // 34 x 10 halo region
  __shared__ u64 skey[256];
  int bb, x0, y0;
  tile_coords(bb, x0, y0);
  const float* fb = feat + (size_t)bb * 3 * NPIX;
  int tid = (int)threadIdx.x;
  skey[tid] = 0;
  for (int c = tid; c < 340; c += 256) {
    int cx = (c % 34) - 1, cy = (c / 34) - 1;
    int x = x0 + cx, y = y0 + cy;
    if (x >= 0 && x < WW && y >= 0 && y < HH) {
      float col[3];
      float g = d_colg(fb, y * WW + x, x, y, col);
      scolg[c] = make_float4(col[0], col[1], col[2], g);
    }
  }
  __syncthreads();
  int tx = tid & 31, ty = tid >> 5;
  int x = x0 + tx, y = y0 + ty;
  int n = y * WW + x;
  int idx = (bb << NSH) + n;
  int cell = (ty + 1) * 34 + (tx + 1);
  float4 ca = scolg[cell];
  labels[idx] = n;
  cnt[idx] = 1;
  pix4[idx] = ca;
  mcol4[idx] = ca;   // level-0 region mean == pixel (exact: x/1.0)
  u64 key = 0;
  if (x < WW - 1) {              // right edge
    u64 s = d_simbits(ca, scolg[cell + 1]);
    key = umax64(key, s | (u32)(NPIX - (n + 1)));
    if (tx < 31) atomicMax(&skey[tid + 1], s | (u32)(NPIX - n));
  }
  if (tx == 0 && x > 0) {        // left boundary edge (solo)
    u64 s = d_simbits(ca, scolg[cell - 1]);
    key = umax64(key, s | (u32)(NPIX - (n - 1)));
  }
  if (y < HH - 1) {              // down edge
    u64 s = d_simbits(ca, scolg[cell + 34]);
    key = umax64(key, s | (u32)(NPIX - (n + WW)));
    if (ty < 7) atomicMax(&skey[tid + 32], s | (u32)(NPIX - n));
  }
  if (ty == 0 && y > 0) {        // up boundary edge (solo)
    u64 s = d_simbits(ca, scolg[cell - 34]);
    key = umax64(key, s | (u32)(NPIX - (n - WW)));
  }
  __syncthreads();
  bnkey[idx] = umax64(key, skey[tid]);
}

// levels >=1 edge pass, tiled with shared sims. NEW: instead of writing a
// per-pixel key (and aggregating to rep slots in a separate k_reduce pass),
// each pixel fire-and-forget atomicMax-es its final key DIRECTLY into its
// rep's slot of the pre-zeroed ping-pong buffer bnext. Max is associative ->
// bit-identical to the old reduce. No return dependency, addresses spread
// over ~1M rep slots (<=8-way same-address contention), same-XCD L2 under
// the slab swizzle. This deletes k_reduce entirely (3 dispatches: cnt read +
// mem-list gather + member-key gather + rewrite, per level).
__global__ __launch_bounds__(256) void k_edge(const int* __restrict__ labels,
                                              const float4* __restrict__ mcol4,
                                              u64* __restrict__ bnext) {
  __shared__ int sla[256];
  __shared__ float4 sma[256];
  __shared__ u64 skey[256];
  int bb, x0, y0;
  tile_coords(bb, x0, y0);
  int tid = (int)threadIdx.x;
  int tx = tid & 31, ty = tid >> 5;
  int x = x0 + tx, y = y0 + ty;
  int n = y * WW + x;
  int base = bb << NSH;
  int idx = base + n;
  int la = labels[idx];
  float4 ma = mcol4[base + la];
  sla[tid] = la;
  sma[tid] = ma;
  skey[tid] = 0;
  __syncthreads();
  u64 key = 0;
  if (x < WW - 1) {              // right edge
    if (tx < 31) {
      int lb = sla[tid + 1];
      if (lb != la) {
        u64 s = d_simbits(ma, sma[tid + 1]);
        key = umax64(key, s | (u32)(NPIX - lb));
        atomicMax(&skey[tid + 1], s | (u32)(NPIX - la));
      }
    } else {
      int lb = labels[idx + 1];
      if (lb != la) key = umax64(key, d_simbits(ma, mcol4[base + lb]) | (u32)(NPIX - lb));
    }
  }
  if (tx == 0 && x > 0) {        // left boundary edge (solo)
    int lb = labels[idx - 1];
    if (lb != la) key = umax64(key, d_simbits(ma, mcol4[base + lb]) | (u32)(NPIX - lb));
  }
  if (y < HH - 1) {              // down edge
    if (ty < 7) {
      int lb = sla[tid + 32];
      if (lb != la) {
        u64 s = d_simbits(ma, sma[tid + 32]);
        key = umax64(key, s | (u32)(NPIX - lb));
        atomicMax(&skey[tid + 32], s | (u32)(NPIX - la));
      }
    } else {
      int lb = labels[idx + WW];
      if (lb != la) key = umax64(key, d_simbits(ma, mcol4[base + lb]) | (u32)(NPIX - lb));
    }
  }
  if (ty == 0 && y > 0) {        // up boundary edge (solo)
    int lb = labels[idx - WW];
    if (lb != la) key = umax64(key, d_simbits(ma, mcol4[base + lb]) | (u32)(NPIX - lb));
  }
  __syncthreads();
  u64 val = umax64(key, skey[tid]);
  if (val) atomicMax(&bnext[base + la], val);
}

// fused scan + pair processing with LDS-level compaction. NEW vs round 3:
// (a) coalesced-zeroes the OTHER ping-pong key buffer for the next level's
//     k_edge atomics (race-free: nothing else touches bnext in this kernel,
//     and kernel ordering sequences it before the next edge pass);
// (b) mem lists are u16 offsets relative to the rep (member-rep in
//     [0, 15*512+15] -- region diameter <=15 and rep = min id), halving the
//     mem stride (64->32B) and all its gather/write bytes.
// Scan reads rep-slot keys (aggregated by k_edge's atomics; singleton reps
// got their own pixel's atomic). Fusion safety & merge-body aliasing notes:
// see round-2 version (unchanged).
template<bool LVL0, bool ZNEXT>
__global__ __launch_bounds__(256) void k_scanpairs(int* __restrict__ labels,
                                                   int* __restrict__ cnt,
                                                   u16* __restrict__ mem,
                                                   const u64* __restrict__ bnkey,
                                                   u64* __restrict__ bnext,
                                                   const float4* __restrict__ pix4,
                                                   float4* __restrict__ mcol4, int total) {
  __shared__ u64 swl[256];
  __shared__ int scnt;
  if (threadIdx.x == 0) scnt = 0;
  __syncthreads();

  int idx = swz_idx();
  if (ZNEXT && idx < total) bnext[idx] = 0;   // pre-zero next level's key buffer
  bool pred = false;
  u64 e = 0;
  if (idx < total) {
    int n = idx & (NPIX - 1);
    int base = idx - n;
    int c = 1;
    bool live = true;
    if (!LVL0) { c = cnt[idx]; live = (c > 0); }
    if (live) {
      u64 K = bnkey[idx];
      int v = NPIX - (int)(K & 0xffffffffu);   // K==0 -> v==NPIX
      if (v < NPIX && n < v) {                  // only the min side acts
        u64 Kv = bnkey[base + v];
        if (NPIX - (int)(Kv & 0xffffffffu) == n) {   // mutual
          pred = true;
          e = ((u64)(u32)idx << 32) | ((u64)(u32)c << 18) | (u32)v;
        }
      }
    }
  }

  u64 mask = __ballot(pred);
  int lane = (int)(threadIdx.x & 63);
  int wb0 = 0;
  if (lane == 0 && mask) wb0 = atomicAdd(&scnt, __popcll(mask));
  int wb = __shfl(wb0, 0);
  if (pred) {
    int pos = wb + __popcll(mask & ((1ull << lane) - 1ull));
    swl[pos] = e;
  }
  __syncthreads();
  int m = scnt;
  if ((int)threadIdx.x >= m) return;

  e = swl[threadIdx.x];
  int idx2 = (int)(e >> 32);
  int v = (int)(e & 0x3ffffu);
  int n = idx2 & (NPIX - 1);
  int base = idx2 - n;
  float s0, s1, s2, sg;
  int k;
  u16* mo = mem + ((size_t)idx2 << 4);
  if (LVL0) {
    k = 2;
    float4 pa = pix4[idx2];
    float4 pb = pix4[base + v];
    s0 = __fadd_rn(__fadd_rn(0.f, pa.x), pb.x);
    s1 = __fadd_rn(__fadd_rn(0.f, pa.y), pb.y);
    s2 = __fadd_rn(__fadd_rn(0.f, pa.z), pb.z);
    sg = __fadd_rn(__fadd_rn(0.f, pa.w), pb.w);
    mo[0] = 0; mo[1] = (u16)(v - n);
    labels[idx2] = n;
    labels[base + v] = n;
  } else {
    int c = (int)((e >> 18) & 0x1fu);
    int cb = cnt[base + v];
    const u16* ma = mem + ((size_t)idx2 << 4);
    const u16* mb = mem + ((size_t)(base + v) << 4);
    k = c + cb;
    s0 = s1 = s2 = sg = 0.f;
    int i = 0, j = 0;
    while (i < c || j < cb) {
      int av = (i < c) ? ((c == 1) ? n : n + (int)ma[i]) : 0x7fffffff;
      int bv = (j < cb) ? ((cb == 1) ? v : v + (int)mb[j]) : 0x7fffffff;
      int x;
      if (av < bv) { x = av; ++i; } else { x = bv; ++j; }
      float4 p = pix4[base + x];
      s0 = __fadd_rn(s0, p.x);
      s1 = __fadd_rn(s1, p.y);
      s2 = __fadd_rn(s2, p.z);
      sg = __fadd_rn(sg, p.w);
      labels[base + x] = n;
    }
    int i2 = c - 1, j2 = cb - 1;
    for (int t2 = k - 1; t2 >= 0; --t2) {
      int av = (i2 >= 0) ? ((c == 1) ? n : n + (int)ma[i2]) : (int)0x80000000;
      int bv = (j2 >= 0) ? ((cb == 1) ? v : v + (int)mb[j2]) : (int)0x80000000;
      int x;
      if (av > bv) { x = av; --i2; } else { x = bv; --j2; }
      mo[t2] = (u16)(x - n);
    }
  }
  float safe = (float)k;
  mcol4[idx2] = make_float4(__fdiv_rn(s0, safe), __fdiv_rn(s1, safe),
                            __fdiv_rn(s2, safe), __fdiv_rn(sg, safe));
  cnt[idx2] = k;
  cnt[base + v] = 0;
}

// write labels (as f32) + region-mean color map
__global__ __launch_bounds__(256) void k_out(const int* __restrict__ labels,
                                             const float4* __restrict__ mcol4,
                                             float* __restrict__ out, int total,
                                             int b0, int Btot) {
  int idx = swz_idx();
  if (idx >= total) return;
  int b = idx >> NSH;
  int n = idx & (NPIX - 1);
  int l = labels[idx];
  out[(size_t)(b0 + b) * NPIX + n] = (float)l;
  size_t cb = (size_t)Btot * NPIX;
  float4 m = mcol4[(size_t)(b << NSH) + l];
  out[cb + ((size_t)(b0 + b) * 3 + 0) * NPIX + n] = m.x;
  out[cb + ((size_t)(b0 + b) * 3 + 1) * NPIX + n] = m.y;
  out[cb + ((size_t)(b0 + b) * 3 + 2) * NPIX + n] = m.z;
}

extern "C" void kernel_launch(void* const* d_in, const int* in_sizes, int n_in,
                              void* d_out, int out_size, void* d_ws, size_t ws_size,
                              hipStream_t stream) {
  const float* feat = (const float*)d_in[0];
  float* out = (float*)d_out;
  int Btot = in_sizes[0] / (3 * NPIX);

  // per-pixel ws bytes:
  //   mcol4 16 + pix4 16 + keyA 8 + keyB 8 + labels 4 + cnt 4 + mem(u16x16) 32 = 88
  const size_t perB = (size_t)NPIX * 88;
  int nbmax = (int)(ws_size / perB);
  if (nbmax < 1) nbmax = 1;
  if (nbmax > Btot) nbmax = Btot;

  for (int b0 = 0; b0 < Btot; b0 += nbmax) {
    int nb = (Btot - b0 < nbmax) ? (Btot - b0) : nbmax;
    size_t cn = (size_t)nb << NSH;
    char* p = (char*)d_ws;
    float4* mcol4 = (float4*)p; p += cn * 16;   // 16B-aligned first
    float4* pix4 = (float4*)p;  p += cn * 16;
    u64* keyA = (u64*)p;        p += cn * 8;
    u64* keyB = (u64*)p;        p += cn * 8;
    int* labels = (int*)p;      p += cn * 4;
    int* cnt = (int*)p;         p += cn * 4;
    u16* mem = (u16*)p;

    const float* fchunk = feat + (size_t)b0 * 3 * NPIX;
    int total = (int)cn;
    int grid = total >> 8;    // nb*1024 blocks, divisible by 8 (swizzle req.)

    // ping-pong: prep->A; sp0 reads A, zeroes B; edge1->B; sp1 reads B,
    // zeroes A; edge2->A; sp2 reads A, zeroes B; edge3->B; sp3 reads B.
    k_prep0edge<<<grid, 256, 0, stream>>>(fchunk, labels, cnt, pix4, mcol4, keyA);
    k_scanpairs<true, true><<<grid, 256, 0, stream>>>(labels, cnt, mem, keyA, keyB,
                                                      pix4, mcol4, total);
    k_edge<<<grid, 256, 0, stream>>>(labels, mcol4, keyB);
    k_scanpairs<false, true><<<grid, 256, 0, stream>>>(labels, cnt, mem, keyB, keyA,
                                                       pix4, mcol4, total);
    k_edge<<<grid, 256, 0, stream>>>(labels, mcol4, keyA);
    k_scanpairs<false, true><<<grid, 256, 0, stream>>>(labels, cnt, mem, keyA, keyB,
                                                       pix4, mcol4, total);
    k_edge<<<grid, 256, 0, stream>>>(labels, mcol4, keyB);
    k_scanpairs<false, false><<<grid, 256, 0, stream>>>(labels, cnt, mem, keyB, keyA,
                                                        pix4, mcol4, total);
    k_out<<<grid, 256, 0, stream>>>(labels, mcol4, out, total, b0, Btot);
  }
}

// Round 5
// 292.172 us; speedup vs baseline: 6.5623x; 1.0469x over previous
//
#include <hip/hip_runtime.h>
#include <math.h>

#define WW 512
#define HH 512
#define NPIX (WW*HH)
#define NSH 18  /* log2(NPIX) */
#define NXCD 8

typedef unsigned long long u64;
typedef unsigned int u32;
typedef unsigned short u16;

__device__ __forceinline__ u64 umax64(u64 a, u64 b) { return a > b ? a : b; }

// XCD-contiguous block remap for the 1-D kernels (scanpairs/out).
// Grid is always nb*1024 -> divisible by 8, so this is a bijection. Each XCD
// gets a contiguous slab of pixel slots (at nb=8: one image per XCD) so
// neighbor-indexed reads hit the issuing XCD's own L2.
__device__ __forceinline__ int swz_idx() {
  int g = gridDim.x;
  int b = (int)blockIdx.x;
  int nb2 = (b & (NXCD - 1)) * (g >> 3) + (b >> 3);
  return nb2 * 256 + (int)threadIdx.x;
}

// Tile mapping for the 2-D edge kernels: 32x8-pixel tiles, 16x64 tiles per
// image, XCD-slab swizzled the same way (at nb=8 each XCD owns one image, so
// rep-slot atomics and halo reads stay in one XCD's L2).
__device__ __forceinline__ void tile_coords(int& bb, int& x0, int& y0) {
  int g = gridDim.x;
  int b = (int)blockIdx.x;
  int t = (b & (NXCD - 1)) * (g >> 3) + (b >> 3);
  bb = t >> 10;
  int rem = t & 1023;
  y0 = (rem >> 4) << 3;   // tile row * 8
  x0 = (rem & 15) << 5;   // tile col * 32
}

// colors + gradient magnitude of pixel p (same __f*_rn sequence as always ->
// bit-identical to the reference's XLA lowering)
__device__ __forceinline__ float d_colg(const float* __restrict__ fb, int p, int pw, int ph,
                                        float col[3]) {
  float s = 0.f;
#pragma unroll
  for (int c = 0; c < 3; ++c) {
    const float* fc = fb + (size_t)c * NPIX;
    float v = fc[p];
    col[c] = v;
    float gx = (pw < WW - 1) ? __fsub_rn(fc[p + 1], v) : 0.f;
    float gy = (ph < HH - 1) ? __fsub_rn(fc[p + WW], v) : 0.f;
    float g = __fsqrt_rn(__fadd_rn(__fadd_rn(__fmul_rn(gx, gx), __fmul_rn(gy, gy)), 1e-12f));
    s = __fadd_rn(s, g);
  }
  return __fdiv_rn(s, 3.0f);
}

// sim bits (<<32) for the undirected edge between means a and b. Bitwise
// symmetric -> ONE exp serves both endpoints; only the tiebreak low word
// (NPIX-lb) is per-side. Sequence identical to the original d_simkey.
// sim in (0,1] -> sim_bits <= 0x3f800000 < 2^30 -> key bits 62-63 are FREE.
// They carry the level tag (see k_edge): atomicMax is monotone in the tag,
// so level-L entries dominate stale level-(L-1) entries -> the key buffer is
// never zeroed and never ping-ponged.
__device__ __forceinline__ u64 d_simbits(float4 a, float4 b) {
  float d0 = __fsub_rn(a.x, b.x);
  float d1 = __fsub_rn(a.y, b.y);
  float d2 = __fsub_rn(a.z, b.z);
  float ss = __fadd_rn(__fadd_rn(__fmul_rn(d0, d0), __fmul_rn(d1, d1)), __fmul_rn(d2, d2));
  float dc = __fsqrt_rn(__fadd_rn(ss, 1e-12f));
  float ge = __fmul_rn(0.5f, __fadd_rn(a.w, b.w));
  float t = __fadd_rn(__fdiv_rn(dc, 10.0f), __fdiv_rn(ge, 27.8f));
  float sim = (float)exp(-(double)t);   // ~correctly-rounded expf
  return ((u64)__float_as_uint(sim)) << 32;
}

// fused prep + level-0 edge pass, tiled (unchanged). Writes level-0 keys
// coalesced (tag 0: sim bits never reach bits 62-63) -- fully initializes
// the single key buffer.
__global__ __launch_bounds__(256) void k_prep0edge(const float* __restrict__ feat,
                                                   int* __restrict__ labels,
                                                   int* __restrict__ cnt,
                                                   float4* __restrict__ pix4,
                                                   float4* __restrict__ mcol4,
                                                   u64* __restrict__ bnkey) {
  __shared__ float4 scolg[340];   // 34 x 10 halo region
  __shared__ u64 skey[256];
  int bb, x0, y0;
  tile_coords(bb, x0, y0);
  const float* fb = feat + (size_t)bb * 3 * NPIX;
  int tid = (int)threadIdx.x;
  skey[tid] = 0;
  for (int c = tid; c < 340; c += 256) {
    int cx = (c % 34) - 1, cy = (c / 34) - 1;
    int x = x0 + cx, y = y0 + cy;
    if (x >= 0 && x < WW && y >= 0 && y < HH) {
      float col[3];
      float g = d_colg(fb, y * WW + x, x, y, col);
      scolg[c] = make_float4(col[0], col[1], col[2], g);
    }
  }
  __syncthreads();
  int tx = tid & 31, ty = tid >> 5;
  int x = x0 + tx, y = y0 + ty;
  int n = y * WW + x;
  int idx = (bb << NSH) + n;
  int cell = (ty + 1) * 34 + (tx + 1);
  float4 ca = scolg[cell];
  labels[idx] = n;
  cnt[idx] = 1;
  pix4[idx] = ca;
  mcol4[idx] = ca;   // level-0 region mean == pixel (exact: x/1.0)
  u64 key = 0;
  if (x < WW - 1) {              // right edge
    u64 s = d_simbits(ca, scolg[cell + 1]);
    key = umax64(key, s | (u32)(NPIX - (n + 1)));
    if (tx < 31) atomicMax(&skey[tid + 1], s | (u32)(NPIX - n));
  }
  if (tx == 0 && x > 0) {        // left boundary edge (solo)
    u64 s = d_simbits(ca, scolg[cell - 1]);
    key = umax64(key, s | (u32)(NPIX - (n - 1)));
  }
  if (y < HH - 1) {              // down edge
    u64 s = d_simbits(ca, scolg[cell + 34]);
    key = umax64(key, s | (u32)(NPIX - (n + WW)));
    if (ty < 7) atomicMax(&skey[tid + 32], s | (u32)(NPIX - n));
  }
  if (ty == 0 && y > 0) {        // up boundary edge (solo)
    u64 s = d_simbits(ca, scolg[cell - 34]);
    key = umax64(key, s | (u32)(NPIX - (n - WW)));
  }
  __syncthreads();
  bnkey[idx] = umax64(key, skey[tid]);
}

// levels >=1 edge pass, tiled with shared sims. Each pixel fire-and-forget
// atomicMax-es its level-tagged key directly into its rep's slot of the
// SINGLE key buffer (tag monotonicity replaces zeroing -- see d_simbits).
// All entries for one level share the tag, so the max over them is exactly
// the old {segment_max sim, segment_min label} semantics. Addresses spread
// over ~1M live reps, same-XCD L2 under the slab swizzle.
__global__ __launch_bounds__(256) void k_edge(const int* __restrict__ labels,
                                              const float4* __restrict__ mcol4,
                                              u64* __restrict__ bnkey, int lvl) {
  __shared__ int sla[256];
  __shared__ float4 sma[256];
  __shared__ u64 skey[256];
  int bb, x0, y0;
  tile_coords(bb, x0, y0);
  int tid = (int)threadIdx.x;
  int tx = tid & 31, ty = tid >> 5;
  int x = x0 + tx, y = y0 + ty;
  int n = y * WW + x;
  int base = bb << NSH;
  int idx = base + n;
  int la = labels[idx];
  float4 ma = mcol4[base + la];
  sla[tid] = la;
  sma[tid] = ma;
  skey[tid] = 0;
  __syncthreads();
  u64 key = 0;
  if (x < WW - 1) {              // right edge
    if (tx < 31) {
      int lb = sla[tid + 1];
      if (lb != la) {
        u64 s = d_simbits(ma, sma[tid + 1]);
        key = umax64(key, s | (u32)(NPIX - lb));
        atomicMax(&skey[tid + 1], s | (u32)(NPIX - la));
      }
    } else {
      int lb = labels[idx + 1];
      if (lb != la) key = umax64(key, d_simbits(ma, mcol4[base + lb]) | (u32)(NPIX - lb));
    }
  }
  if (tx == 0 && x > 0) {        // left boundary edge (solo)
    int lb = labels[idx - 1];
    if (lb != la) key = umax64(key, d_simbits(ma, mcol4[base + lb]) | (u32)(NPIX - lb));
  }
  if (y < HH - 1) {              // down edge
    if (ty < 7) {
      int lb = sla[tid + 32];
      if (lb != la) {
        u64 s = d_simbits(ma, sma[tid + 32]);
        key = umax64(key, s | (u32)(NPIX - lb));
        atomicMax(&skey[tid + 32], s | (u32)(NPIX - la));
      }
    } else {
      int lb = labels[idx + WW];
      if (lb != la) key = umax64(key, d_simbits(ma, mcol4[base + lb]) | (u32)(NPIX - lb));
    }
  }
  if (ty == 0 && y > 0) {        // up boundary edge (solo)
    int lb = labels[idx - WW];
    if (lb != la) key = umax64(key, d_simbits(ma, mcol4[base + lb]) | (u32)(NPIX - lb));
  }
  __syncthreads();
  u64 val = umax64(key, skey[tid]);
  if (val) atomicMax(&bnkey[base + la], ((u64)lvl << 62) | val);
}

// fused scan + pair processing with LDS-level compaction. Changes this round:
// (a) scan reads ONLY bnkey: tag==lvl <=> slot is a live rep with level-lvl
//     edges (atomics target labels[] values = live reps; every live region
//     has a boundary). cnt liveness read deleted; c/cb counts move to the
//     pairs phase (read only for actual pairs).
// (b) no buffer zeroing (tag monotonicity, see d_simbits).
// (c) LAST level: nothing reads mem/cnt[rep]/labels afterwards except k_out,
//     so skip the member label scatter + merged-list write + cnt[rep] write;
//     instead store a forwarding marker cnt[absorbed] = -newrep which k_out
//     resolves (stale positive cnt elsewhere is fine -- only the sign is
//     inspected).
// Fusion safety & merge-body aliasing notes: see round-2 version (unchanged).
template<bool LVL0, bool LAST>
__global__ __launch_bounds__(256) void k_scanpairs(int* __restrict__ labels,
                                                   int* __restrict__ cnt,
                                                   u16* __restrict__ mem,
                                                   const u64* __restrict__ bnkey,
                                                   const float4* __restrict__ pix4,
                                                   float4* __restrict__ mcol4,
                                                   int total, int lvl) {
  __shared__ u64 swl[256];
  __shared__ int scnt;
  if (threadIdx.x == 0) scnt = 0;
  __syncthreads();

  int idx = swz_idx();
  bool pred = false;
  u64 e = 0;
  if (idx < total) {
    int n = idx & (NPIX - 1);
    int base = idx - n;
    u64 K = bnkey[idx];
    bool valid = LVL0 ? true : ((int)(K >> 62) == lvl);   // tag==lvl => live rep
    if (valid) {
      int v = NPIX - (int)(K & 0xffffffffu);
      if (v < NPIX && n < v) {                  // only the min side acts
        u64 Kv = bnkey[base + v];
        bool pv = LVL0 ? true : ((int)(Kv >> 62) == lvl);
        if (pv && NPIX - (int)(Kv & 0xffffffffu) == n) {   // mutual
          pred = true;
          e = ((u64)(u32)idx << 32) | (u32)v;
        }
      }
    }
  }

  u64 mask = __ballot(pred);
  int lane = (int)(threadIdx.x & 63);
  int wb0 = 0;
  if (lane == 0 && mask) wb0 = atomicAdd(&scnt, __popcll(mask));
  int wb = __shfl(wb0, 0);
  if (pred) {
    int pos = wb + __popcll(mask & ((1ull << lane) - 1ull));
    swl[pos] = e;
  }
  __syncthreads();
  int m = scnt;
  if ((int)threadIdx.x >= m) return;

  e = swl[threadIdx.x];
  int idx2 = (int)(e >> 32);
  int v = (int)(e & 0xffffffffu);
  int n = idx2 & (NPIX - 1);
  int base = idx2 - n;
  float s0, s1, s2, sg;
  int k;
  u16* mo = mem + ((size_t)idx2 << 4);
  if (LVL0) {
    k = 2;
    float4 pa = pix4[idx2];
    float4 pb = pix4[base + v];
    s0 = __fadd_rn(__fadd_rn(0.f, pa.x), pb.x);
    s1 = __fadd_rn(__fadd_rn(0.f, pa.y), pb.y);
    s2 = __fadd_rn(__fadd_rn(0.f, pa.z), pb.z);
    sg = __fadd_rn(__fadd_rn(0.f, pa.w), pb.w);
    mo[0] = 0; mo[1] = (u16)(v - n);
    labels[idx2] = n;
    labels[base + v] = n;
  } else {
    int c = cnt[idx2];
    int cb = cnt[base + v];
    const u16* ma = mem + ((size_t)idx2 << 4);
    const u16* mb = mem + ((size_t)(base + v) << 4);
    k = c + cb;
    s0 = s1 = s2 = sg = 0.f;
    int i = 0, j = 0;
    while (i < c || j < cb) {
      int av = (i < c) ? ((c == 1) ? n : n + (int)ma[i]) : 0x7fffffff;
      int bv = (j < cb) ? ((cb == 1) ? v : v + (int)mb[j]) : 0x7fffffff;
      int x;
      if (av < bv) { x = av; ++i; } else { x = bv; ++j; }
      float4 p = pix4[base + x];
      s0 = __fadd_rn(s0, p.x);
      s1 = __fadd_rn(s1, p.y);
      s2 = __fadd_rn(s2, p.z);
      sg = __fadd_rn(sg, p.w);
      if (!LAST) labels[base + x] = n;
    }
    if (!LAST) {
      int i2 = c - 1, j2 = cb - 1;
      for (int t2 = k - 1; t2 >= 0; --t2) {
        int av = (i2 >= 0) ? ((c == 1) ? n : n + (int)ma[i2]) : (int)0x80000000;
        int bv = (j2 >= 0) ? ((cb == 1) ? v : v + (int)mb[j2]) : (int)0x80000000;
        int x;
        if (av > bv) { x = av; --i2; } else { x = bv; --j2; }
        mo[t2] = (u16)(x - n);
      }
    }
  }
  float safe = (float)k;
  mcol4[idx2] = make_float4(__fdiv_rn(s0, safe), __fdiv_rn(s1, safe),
                            __fdiv_rn(s2, safe), __fdiv_rn(sg, safe));
  if (LAST) {
    cnt[base + v] = -n;          // forwarding marker for k_out (n==0 -> 0, c<=0 path)
  } else {
    cnt[idx2] = k;
    cnt[base + v] = 0;
  }
}

// write labels (as f32) + region-mean color map. Resolves the LAST-level
// forwarding marker: cnt[l] <= 0 means l was absorbed at the final level by
// rep -cnt[l] (min-side reps keep stale positive cnt -> untouched).
__global__ __launch_bounds__(256) void k_out(const int* __restrict__ labels,
                                             const int* __restrict__ cnt,
                                             const float4* __restrict__ mcol4,
                                             float* __restrict__ out, int total,
                                             int b0, int Btot) {
  int idx = swz_idx();
  if (idx >= total) return;
  int b = idx >> NSH;
  int n = idx & (NPIX - 1);
  int base = b << NSH;
  int l = labels[idx];
  int c2 = cnt[base + l];
  if (c2 <= 0) l = -c2;
  out[(size_t)(b0 + b) * NPIX + n] = (float)l;
  size_t cb = (size_t)Btot * NPIX;
  float4 m = mcol4[base + l];
  out[cb + ((size_t)(b0 + b) * 3 + 0) * NPIX + n] = m.x;
  out[cb + ((size_t)(b0 + b) * 3 + 1) * NPIX + n] = m.y;
  out[cb + ((size_t)(b0 + b) * 3 + 2) * NPIX + n] = m.z;
}

extern "C" void kernel_launch(void* const* d_in, const int* in_sizes, int n_in,
                              void* d_out, int out_size, void* d_ws, size_t ws_size,
                              hipStream_t stream) {
  const float* feat = (const float*)d_in[0];
  float* out = (float*)d_out;
  int Btot = in_sizes[0] / (3 * NPIX);

  // per-pixel ws bytes:
  //   mcol4 16 + pix4 16 + key 8 + labels 4 + cnt 4 + mem(u16x16) 32 = 80
  const size_t perB = (size_t)NPIX * 80;
  int nbmax = (int)(ws_size / perB);
  if (nbmax < 1) nbmax = 1;
  if (nbmax > Btot) nbmax = Btot;

  for (int b0 = 0; b0 < Btot; b0 += nbmax) {
    int nb = (Btot - b0 < nbmax) ? (Btot - b0) : nbmax;
    size_t cn = (size_t)nb << NSH;
    char* p = (char*)d_ws;
    float4* mcol4 = (float4*)p; p += cn * 16;   // 16B-aligned first
    float4* pix4 = (float4*)p;  p += cn * 16;
    u64* key = (u64*)p;         p += cn * 8;
    int* labels = (int*)p;      p += cn * 4;
    int* cnt = (int*)p;         p += cn * 4;
    u16* mem = (u16*)p;

    const float* fchunk = feat + (size_t)b0 * 3 * NPIX;
    int total = (int)cn;
    int grid = total >> 8;    // nb*1024 blocks, divisible by 8 (swizzle req.)

    k_prep0edge<<<grid, 256, 0, stream>>>(fchunk, labels, cnt, pix4, mcol4, key);
    k_scanpairs<true, false><<<grid, 256, 0, stream>>>(labels, cnt, mem, key,
                                                       pix4, mcol4, total, 0);
    k_edge<<<grid, 256, 0, stream>>>(labels, mcol4, key, 1);
    k_scanpairs<false, false><<<grid, 256, 0, stream>>>(labels, cnt, mem, key,
                                                        pix4, mcol4, total, 1);
    k_edge<<<grid, 256, 0, stream>>>(labels, mcol4, key, 2);
    k_scanpairs<false, false><<<grid, 256, 0, stream>>>(labels, cnt, mem, key,
                                                        pix4, mcol4, total, 2);
    k_edge<<<grid, 256, 0, stream>>>(labels, mcol4, key, 3);
    k_scanpairs<false, true><<<grid, 256, 0, stream>>>(labels, cnt, mem, key,
                                                       pix4, mcol4, total, 3);
    k_out<<<grid, 256, 0, stream>>>(labels, cnt, mcol4, out, total, b0, Btot);
  }
}